// Round 3
// baseline (9283.409 us; speedup 1.0000x reference)
//
#include <hip/hip_runtime.h>
#include <hip/hip_bf16.h>

#define D_MODEL 1024
#define D_INNER 2048
#define DT_RANK 64            // (1024+15)//16
#define D_STATE 16
#define NXP     96            // DT_RANK + 2*D_STATE
#define SEQL    2048
#define NLAYERS 2

// ---------------------------------------------------------------- embed
__global__ __launch_bounds__(256) void embed_k(const int* __restrict__ ids,
                                               const float* __restrict__ emb,
                                               float* __restrict__ x) {
    int l = blockIdx.x;
    int id = ids[l];
    const float* src = emb + (size_t)id * D_MODEL;
    float* dst = x + (size_t)l * D_MODEL;
    for (int d = threadIdx.x; d < D_MODEL; d += 256) dst[d] = src[d];
}

// ---------------------------------------------------------------- layernorm (one row per block)
__global__ __launch_bounds__(256) void ln_k(const float* __restrict__ x,
                                            const float* __restrict__ g,
                                            const float* __restrict__ b,
                                            float* __restrict__ out) {
    int l = blockIdx.x;
    const float* xr = x + (size_t)l * D_MODEL;
    float s = 0.f, s2 = 0.f;
    for (int d = threadIdx.x; d < D_MODEL; d += 256) {
        float v = xr[d];
        s += v; s2 += v * v;
    }
    __shared__ float red[2][4];
    for (int off = 32; off; off >>= 1) {
        s  += __shfl_down(s,  off);
        s2 += __shfl_down(s2, off);
    }
    int wid = threadIdx.x >> 6, lid = threadIdx.x & 63;
    if (lid == 0) { red[0][wid] = s; red[1][wid] = s2; }
    __syncthreads();
    float ts  = red[0][0] + red[0][1] + red[0][2] + red[0][3];
    float ts2 = red[1][0] + red[1][1] + red[1][2] + red[1][3];
    float mean = ts * (1.0f / D_MODEL);
    float var  = ts2 * (1.0f / D_MODEL) - mean * mean;
    float rstd = rsqrtf(var + 1e-5f);
    float* o = out + (size_t)l * D_MODEL;
    for (int d = threadIdx.x; d < D_MODEL; d += 256)
        o[d] = (xr[d] - mean) * rstd * g[d] + b[d];
}

// ---------------------------------------------------------------- NT GEMM: C[M,N] = A[M,K] * B[N,K]^T
// A: f32 row-major (lda), B: f32 row-major (ldb). f32 accumulate.
// EPI: 0 = plain f32 store, 1 = softplus(c + bias[n]) f32, 2 = c + resid f32
#define BM 64
#define BN 64
#define BK 16
template <int EPI>
__global__ __launch_bounds__(256) void gemm_nt(const float* __restrict__ A, int lda,
                                               const float* __restrict__ B, int ldb,
                                               float* __restrict__ C, int ldc,
                                               int M, int N, int K,
                                               const float* __restrict__ bias,
                                               const float* __restrict__ resid) {
    __shared__ float As[BK][BM + 1];
    __shared__ float Bs[BK][BN + 1];
    int m0 = blockIdx.y * BM;
    int n0 = blockIdx.x * BN;
    int t = threadIdx.x;
    int tx = t & 15, ty = t >> 4;
    float acc[4][4] = {};
    for (int kb = 0; kb < K; kb += BK) {
#pragma unroll
        for (int i = 0; i < 4; i++) {
            int e = t + i * 256;
            int k = e & 15, m = e >> 4;
            int gk = kb + k;
            int gm = m0 + m;
            As[k][m] = (gm < M && gk < K) ? A[(size_t)gm * lda + gk] : 0.0f;
            int gn = n0 + m;
            Bs[k][m] = (gn < N && gk < K) ? B[(size_t)gn * ldb + gk] : 0.0f;
        }
        __syncthreads();
#pragma unroll
        for (int kk = 0; kk < BK; kk++) {
            float a[4], b[4];
#pragma unroll
            for (int i = 0; i < 4; i++) a[i] = As[kk][ty * 4 + i];
#pragma unroll
            for (int j = 0; j < 4; j++) b[j] = Bs[kk][tx * 4 + j];
#pragma unroll
            for (int i = 0; i < 4; i++)
#pragma unroll
                for (int j = 0; j < 4; j++) acc[i][j] += a[i] * b[j];
        }
        __syncthreads();
    }
#pragma unroll
    for (int i = 0; i < 4; i++) {
        int m = m0 + ty * 4 + i;
        if (m >= M) continue;
#pragma unroll
        for (int j = 0; j < 4; j++) {
            int n = n0 + tx * 4 + j;
            if (n >= N) continue;
            float c = acc[i][j];
            if (EPI == 0) {
                C[(size_t)m * ldc + n] = c;
            } else if (EPI == 1) {
                float v = c + bias[n];
                C[(size_t)m * ldc + n] = (v > 20.f) ? v : log1pf(expf(v));
            } else {
                C[(size_t)m * ldc + n] = c + resid[(size_t)m * ldc + n];
            }
        }
    }
}

// ---------------------------------------------------------------- causal depthwise conv(4) + SiLU
__global__ __launch_bounds__(256) void conv_silu_k(const float* __restrict__ xz,
                                                   const float* __restrict__ cw,
                                                   const float* __restrict__ cb,
                                                   float* __restrict__ xc) {
    int idx = blockIdx.x * 256 + threadIdx.x;       // SEQL * D_INNER threads
    int d = idx & (D_INNER - 1);
    int l = idx >> 11;
    float acc = cb[d];
#pragma unroll
    for (int k = 0; k < 4; k++) {
        int ls = l + k - 3;
        if (ls >= 0) acc += xz[(size_t)ls * (2 * D_INNER) + d] * cw[d * 4 + k];
    }
    acc = acc / (1.0f + expf(-acc));                // silu
    xc[(size_t)l * D_INNER + d] = acc;
}

// ---------------------------------------------------------------- selective scan
// 16 lanes per channel (one per state), 16 channels per 256-thread block.
__global__ __launch_bounds__(256) void scan_k(const float* __restrict__ dt,
                                              const float* __restrict__ xdbl,
                                              const float* __restrict__ xc,
                                              const float* __restrict__ xz,
                                              const float* __restrict__ A_log,
                                              const float* __restrict__ D_skip,
                                              float* __restrict__ y) {
    int t = threadIdx.x;
    int n = t & 15;
    int c = t >> 4;
    int d = blockIdx.x * 16 + c;
    float Ac = -expf(A_log[d * D_STATE + n]);
    float dsk = D_skip[d];
    float h = 0.0f;
    for (int l = 0; l < SEQL; l++) {
        float dtv = dt[(size_t)l * D_INNER + d];
        float xcv = xc[(size_t)l * D_INNER + d];
        float Bv  = xdbl[(size_t)l * NXP + DT_RANK + n];
        float Cv  = xdbl[(size_t)l * NXP + DT_RANK + D_STATE + n];
        h = expf(dtv * Ac) * h + dtv * Bv * xcv;
        float p = h * Cv;
#pragma unroll
        for (int off = 8; off; off >>= 1) p += __shfl_xor(p, off, 16);
        if (n == 0) {
            float zv = xz[(size_t)l * (2 * D_INNER) + D_INNER + d];
            float yv = (p + dsk * xcv) * (zv / (1.0f + expf(-zv)));
            y[(size_t)l * D_INNER + d] = yv;
        }
    }
}

// ---------------------------------------------------------------- launch
extern "C" void kernel_launch(void* const* d_in, const int* in_sizes, int n_in,
                              void* d_out, int out_size, void* d_ws, size_t ws_size,
                              hipStream_t stream) {
    const int*   ids       = (const int*)d_in[0];
    const float* emb       = (const float*)d_in[1];
    const float* ln_g      = (const float*)d_in[2];
    const float* ln_b      = (const float*)d_in[3];
    const float* in_proj_w = (const float*)d_in[4];
    const float* conv_w    = (const float*)d_in[5];
    const float* conv_b    = (const float*)d_in[6];
    const float* x_proj_w  = (const float*)d_in[7];
    const float* dt_proj_w = (const float*)d_in[8];
    const float* dt_proj_b = (const float*)d_in[9];
    const float* A_log     = (const float*)d_in[10];
    const float* D_skip    = (const float*)d_in[11];
    const float* out_proj_w= (const float*)d_in[12];
    const float* lnf_g     = (const float*)d_in[13];
    const float* lnf_b     = (const float*)d_in[14];
    const float* head_w    = (const float*)d_in[15];
    float* out = (float*)d_out;                        // f32 logits, per reference

    // workspace layout (f32), ~93 MB total; hy doubles as LN-out (SEQL*D_MODEL) and y (SEQL*D_INNER)
    float* ws   = (float*)d_ws;
    float* x    = ws;                                  // SEQL * D_MODEL
    float* hy   = x    + (size_t)SEQL * D_MODEL;       // SEQL * D_INNER (max of both uses)
    float* xz   = hy   + (size_t)SEQL * D_INNER;       // SEQL * 2*D_INNER
    float* xc   = xz   + (size_t)SEQL * 2 * D_INNER;   // SEQL * D_INNER
    float* xdbl = xc   + (size_t)SEQL * D_INNER;       // SEQL * NXP
    float* dt   = xdbl + (size_t)SEQL * NXP;           // SEQL * D_INNER

    embed_k<<<SEQL, 256, 0, stream>>>(ids, emb, x);

    for (int layer = 0; layer < NLAYERS; layer++) {
        ln_k<<<SEQL, 256, 0, stream>>>(x, ln_g + layer * D_MODEL, ln_b + layer * D_MODEL, hy);

        dim3 g1((2 * D_INNER + BN - 1) / BN, (SEQL + BM - 1) / BM);
        gemm_nt<0><<<g1, 256, 0, stream>>>(hy, D_MODEL,
                                           in_proj_w + (size_t)layer * 2 * D_INNER * D_MODEL, D_MODEL,
                                           xz, 2 * D_INNER, SEQL, 2 * D_INNER, D_MODEL,
                                           nullptr, nullptr);

        conv_silu_k<<<(SEQL * D_INNER) / 256, 256, 0, stream>>>(
            xz, conv_w + (size_t)layer * D_INNER * 4, conv_b + (size_t)layer * D_INNER, xc);

        dim3 g2((NXP + BN - 1) / BN, (SEQL + BM - 1) / BM);
        gemm_nt<0><<<g2, 256, 0, stream>>>(xc, D_INNER,
                                           x_proj_w + (size_t)layer * NXP * D_INNER, D_INNER,
                                           xdbl, NXP, SEQL, NXP, D_INNER,
                                           nullptr, nullptr);

        dim3 g3((D_INNER + BN - 1) / BN, (SEQL + BM - 1) / BM);
        gemm_nt<1><<<g3, 256, 0, stream>>>(xdbl, NXP,
                                           dt_proj_w + (size_t)layer * D_INNER * DT_RANK, DT_RANK,
                                           dt, D_INNER, SEQL, D_INNER, DT_RANK,
                                           dt_proj_b + (size_t)layer * D_INNER, nullptr);

        scan_k<<<D_INNER / 16, 256, 0, stream>>>(dt, xdbl, xc, xz,
                                                 A_log + (size_t)layer * D_INNER * D_STATE,
                                                 D_skip + (size_t)layer * D_INNER, hy);

        dim3 g4((D_MODEL + BN - 1) / BN, (SEQL + BM - 1) / BM);
        gemm_nt<2><<<g4, 256, 0, stream>>>(hy, D_INNER,
                                           out_proj_w + (size_t)layer * D_MODEL * D_INNER, D_INNER,
                                           x, D_MODEL, SEQL, D_MODEL, D_INNER,
                                           nullptr, x);
    }

    ln_k<<<SEQL, 256, 0, stream>>>(x, lnf_g, lnf_b, hy);

    dim3 g5((32000 + BN - 1) / BN, (SEQL + BM - 1) / BM);
    gemm_nt<0><<<g5, 256, 0, stream>>>(hy, D_MODEL, head_w, D_MODEL,
                                       out, 32000, SEQL, 32000, D_MODEL,
                                       nullptr, nullptr);
}